// Round 1
// baseline (496.760 us; speedup 1.0000x reference)
//
#include <hip/hip_runtime.h>
#include <hip/hip_bf16.h>
#include <math.h>

typedef __hip_bfloat16 bf16;
typedef unsigned short u16;
#define BF(x) __bfloat162float(x)
static __device__ __forceinline__ bf16 FB(float x) { return __float2bfloat16(x); }
static __device__ __forceinline__ u16 FBu(float x) {
    bf16 b = __float2bfloat16(x);
    return *(u16*)&b;
}

typedef __attribute__((ext_vector_type(4))) float f32x4;
typedef __attribute__((ext_vector_type(8))) __bf16 bf16x8;

// Problem: B=8, H=W=64, C=128, L=4096, NH=4, HD=32, WIN=8, N=64, NW=64, M=32768.

// Wt (prepped bf16 weights) element offsets
#define O_REDW 0
#define O_QKVW 32768
#define O_PW   131072
#define O_F1W  163840
#define O_F2W  294912
#define O_LFW  425984
#define O_GFW  442368
#define O_FFW  458752
#define O_REDB 475136
#define O_QKVB 475264
#define O_PB   476032
#define O_F1B  476288
#define O_F2B  477312
#define O_LFB  477568
#define O_GFB  477696
#define O_FFB  477824
#define O_RP   477952
#define O_N1G  479752
#define O_N1B  480008
#define O_N2G  480264
#define O_N2B  480520
#define O_OW   480776
#define O_OB   481928
#define O_MW   481931
#define O_MB   483083

// Padded LDS tile geometry for VALU-written A-tiles (kills 16-way conflicts):
// row stride 36 u16 (72 B = 18 banks), chunk stride 2320 u16.
#define ROW_S 36
#define CH_S  2320

// Runtime input-dtype detection from xt (N(0,1) data). 0 = bf16, 1 = fp32.
__device__ __forceinline__ int get_mode(const void* xt) {
    const unsigned* w = (const unsigned*)xt;
    int zlo = 0, inband = 0;
    #pragma unroll
    for (int i = 0; i < 32; ++i) {
        unsigned lo = w[i] & 0xFFFFu;
        int e = (int)((lo >> 7) & 0xFF);
        zlo += (lo == 0u || lo == 0x8000u);
        inband += (e >= 100 && e <= 140);
    }
    if (zlo >= 29) return 1;
    return (inband >= 20) ? 0 : 1;
}

__device__ __forceinline__ float LD(const void* p, size_t i, int mode) {
    return mode ? ((const float*)p)[i] : BF(((const bf16*)p)[i]);
}

// async global->LDS, 16 bytes per lane
__device__ __forceinline__ void async16(const u16* g, u16* l) {
    __builtin_amdgcn_global_load_lds(
        (const __attribute__((address_space(1))) unsigned int*)g,
        (__attribute__((address_space(3))) unsigned int*)l, 16, 0, 0);
}

// ---------------------------------------------------------------------------
// Prep: transpose weights to [N][K] bf16 + convert params.
// ---------------------------------------------------------------------------
struct PrepT { const void* src; int srcOff, K, N, dstOff; };
struct Prep { PrepT d[29]; int start[30]; };

__global__ void prep_k(Prep p, bf16* __restrict__ dst, const void* __restrict__ dtp) {
    const int mode = get_mode(dtp);
    int i = blockIdx.x * 256 + threadIdx.x;
    if (i >= p.start[29]) return;
    int s = 0;
    while (p.start[s + 1] <= i) ++s;
    int e = i - p.start[s];
    float v;
    if (p.d[s].N > 0) {
        int n = e / p.d[s].K, k = e % p.d[s].K;
        v = LD(p.d[s].src, (size_t)p.d[s].srcOff + (size_t)k * p.d[s].N + n, mode);
    } else {
        v = LD(p.d[s].src, (size_t)p.d[s].srcOff + e, mode);
    }
    dst[p.d[s].dstOff + e] = FB(v);
}

// Vectorized concat: X[32768][256] = bf16([xt | hx]).  Grid-stride.
__launch_bounds__(256)
__global__ void xcat_k(const void* __restrict__ xt, const void* __restrict__ hx,
                       u16* __restrict__ X) {
    const int mode = get_mode(xt);
    const int total = 32768 * 32;            // groups of 8 elements
    for (int gidx = blockIdx.x * 256 + threadIdx.x; gidx < total;
         gidx += gridDim.x * 256) {
        int r = gidx >> 5, gi = gidx & 31;
        const void* src = (gi < 16) ? xt : hx;
        int c = (gi & 15) << 3;
        u16 outv[8];
        if (mode) {
            const float* s = (const float*)src + (size_t)r * 128 + c;
            float4 a = *(const float4*)s;
            float4 b = *(const float4*)(s + 4);
            outv[0] = FBu(a.x); outv[1] = FBu(a.y); outv[2] = FBu(a.z); outv[3] = FBu(a.w);
            outv[4] = FBu(b.x); outv[5] = FBu(b.y); outv[6] = FBu(b.z); outv[7] = FBu(b.w);
        } else {
            *(uint4*)outv = *(const uint4*)((const u16*)src + (size_t)r * 128 + c);
        }
        *(uint4*)(X + (size_t)r * 256 + (gi << 3)) = *(const uint4*)outv;
    }
}

// ---------------------------------------------------------------------------
// MFMA GEMM 128x128 tile, BK=32. Direct global fragment loads (A in [M][K],
// Bt in [N][K]: each MFMA fragment is 16 contiguous bytes). No LDS, no
// barriers -> waves run free, compiler software-pipelines the k-loop.
// EPI 3: window-reverse/roll scatter-add into outf. 5: fp32 store.
// ---------------------------------------------------------------------------
template <int EPI>
__launch_bounds__(256)
__global__ void gemm_mfma(const u16* __restrict__ A, const u16* __restrict__ Bt,
                          const bf16* __restrict__ bias, bf16* __restrict__ outb,
                          float* __restrict__ outf, int M, int N, int K, int shift) {
    const int tid = threadIdx.x;
    const int wave = tid >> 6, lane = tid & 63;
    const int q = lane >> 4, lr = lane & 15;
    const int wm = (wave >> 1) << 6, wn = (wave & 1) << 6;
    const int bm = blockIdx.y << 7, bn = blockIdx.x << 7;
    const f32x4 zero = {0.f, 0.f, 0.f, 0.f};
    f32x4 acc[4][4];
    #pragma unroll
    for (int i = 0; i < 4; ++i)
        #pragma unroll
        for (int j = 0; j < 4; ++j) acc[i][j] = zero;

    for (int k0 = 0; k0 < K; k0 += 32) {
        bf16x8 af[4], bfr[4];
        #pragma unroll
        for (int t = 0; t < 4; ++t) {
            af[t]  = *(const bf16x8*)(A  + (size_t)(bm + wm + (t << 4) + lr) * K + k0 + (q << 3));
            bfr[t] = *(const bf16x8*)(Bt + (size_t)(bn + wn + (t << 4) + lr) * K + k0 + (q << 3));
        }
        #pragma unroll
        for (int mt = 0; mt < 4; ++mt)
            #pragma unroll
            for (int nt = 0; nt < 4; ++nt)
                acc[mt][nt] = __builtin_amdgcn_mfma_f32_16x16x32_bf16(
                    af[mt], bfr[nt], acc[mt][nt], 0, 0, 0);
    }

    #pragma unroll
    for (int nt = 0; nt < 4; ++nt) {
        int col = bn + wn + (nt << 4) + lr;
        float bv = BF(bias[col]);
        #pragma unroll
        for (int mt = 0; mt < 4; ++mt) {
            int row0 = bm + wm + (mt << 4) + (q << 2);
            #pragma unroll
            for (int i = 0; i < 4; ++i) {
                int r = row0 + i;
                float v = acc[mt][nt][i] + bv;
                size_t idx = (size_t)r * N + col;
                if (EPI == 0) {
                    outb[idx] = FB(v);
                } else if (EPI == 3) {
                    int b = r >> 12, rem = r & 4095;
                    int wi = rem >> 6, n = rem & 63;
                    int hp = ((wi >> 3) << 3) + (n >> 3);
                    int wp = ((wi & 7) << 3) + (n & 7);
                    int h = (hp + shift) & 63, w = (wp + shift) & 63;
                    outf[((size_t)((b << 12) + (h << 6) + w)) * 128 + col] += v;
                } else if (EPI == 5) {
                    outf[idx] = v;
                }
            }
        }
    }
}

// ---------------------------------------------------------------------------
// Fused LN1 (+roll+window gather) + QKV GEMM. Block = 64 windowed rows,
// 512 blocks. LDS: Ach 4x[64][36] padded. B fragments loaded directly from
// global (L2-resident weights) -> no per-nc staging/barriers.
// ---------------------------------------------------------------------------
__launch_bounds__(256)
__global__ void qkvln_k(const float* __restrict__ g, const u16* __restrict__ wtu,
                        const bf16* __restrict__ wtb, u16* __restrict__ qkv,
                        int d, int shift) {
    __shared__ __align__(16) u16 Ach[4 * CH_S];
    const int tid = threadIdx.x;
    const int wave = tid >> 6, lane = tid & 63;
    const int q = lane >> 4, lr = lane & 15;
    const int wm = (wave >> 1) << 5, wn = (wave & 1) << 6;
    const int bm = blockIdx.x << 6;

    // LN1 with inverse-roll gather: thread = (row = tid>>2, qtr = tid&3)
    {
        int row = tid >> 2, qtr = tid & 3;
        int r = bm + row;
        int b = r >> 12, rem = r & 4095;
        int wi = rem >> 6, n = rem & 63;
        int hp = ((wi >> 3) << 3) + (n >> 3);
        int wp = ((wi & 7) << 3) + (n & 7);
        int h = (hp + shift) & 63, w = (wp + shift) & 63;
        int src = (b << 12) + (h << 6) + w;
        const float* gr = g + (size_t)src * 128 + qtr * 32;
        float vals[32];
        float s1 = 0.f, s2 = 0.f;
        #pragma unroll
        for (int i = 0; i < 8; ++i) {
            float4 v4 = *(const float4*)(gr + i * 4);
            vals[i * 4] = v4.x; vals[i * 4 + 1] = v4.y;
            vals[i * 4 + 2] = v4.z; vals[i * 4 + 3] = v4.w;
            s1 += v4.x + v4.y + v4.z + v4.w;
            s2 += v4.x * v4.x + v4.y * v4.y + v4.z * v4.z + v4.w * v4.w;
        }
        s1 += __shfl_xor(s1, 1); s1 += __shfl_xor(s1, 2);
        s2 += __shfl_xor(s2, 1); s2 += __shfl_xor(s2, 2);
        float mu = s1 * (1.f / 128.f);
        float var = s2 * (1.f / 128.f) - mu * mu;
        float inv = rsqrtf(var + 1e-5f);
        #pragma unroll
        for (int i = 0; i < 32; ++i) {
            int c = qtr * 32 + i;
            float o = (vals[i] - mu) * inv * BF(wtb[O_N1G + d * 128 + c])
                      + BF(wtb[O_N1B + d * 128 + c]);
            Ach[qtr * CH_S + row * ROW_S + i] = FBu(o);
        }
    }
    __syncthreads();

    const f32x4 zero = {0.f, 0.f, 0.f, 0.f};
    for (int nc = 0; nc < 3; ++nc) {
        const u16* Bg = wtu + O_QKVW + d * 49152 + nc * 16384;
        f32x4 acc[2][4];
        #pragma unroll
        for (int i = 0; i < 2; ++i)
            #pragma unroll
            for (int j = 0; j < 4; ++j) acc[i][j] = zero;
        #pragma unroll
        for (int k0 = 0; k0 < 4; ++k0) {
            bf16x8 af[2], bfr[4];
            #pragma unroll
            for (int t = 0; t < 2; ++t)
                af[t] = *(const bf16x8*)(Ach + k0 * CH_S + (wm + (t << 4) + lr) * ROW_S + (q << 3));
            #pragma unroll
            for (int t = 0; t < 4; ++t)
                bfr[t] = *(const bf16x8*)(Bg + ((wn + (t << 4) + lr) << 7) + (k0 << 5) + (q << 3));
            #pragma unroll
            for (int mt = 0; mt < 2; ++mt)
                #pragma unroll
                for (int nt = 0; nt < 4; ++nt)
                    acc[mt][nt] = __builtin_amdgcn_mfma_f32_16x16x32_bf16(
                        af[mt], bfr[nt], acc[mt][nt], 0, 0, 0);
        }
        #pragma unroll
        for (int nt = 0; nt < 4; ++nt) {
            int col = wn + (nt << 4) + lr;
            float bv = BF(wtb[O_QKVB + d * 384 + nc * 128 + col]);
            #pragma unroll
            for (int mt = 0; mt < 2; ++mt) {
                #pragma unroll
                for (int i = 0; i < 4; ++i) {
                    int r = bm + wm + (mt << 4) + (q << 2) + i;
                    qkv[(size_t)r * 384 + nc * 128 + col] = FBu(acc[mt][nt][i] + bv);
                }
            }
        }
    }
}

// ---------------------------------------------------------------------------
// Windowed attention: block = one window (4 heads = 4 waves).
// ---------------------------------------------------------------------------
__launch_bounds__(256)
__global__ void attn_k(const u16* __restrict__ qkv, const bf16* __restrict__ rp,
                       u16* __restrict__ outp, int shift) {
    __shared__ float kT[4][32][64];
    __shared__ float vT[4][32][64];
    const int wq = blockIdx.x;
    const int head = threadIdx.x >> 6;
    const int t = threadIdx.x & 63;
    const size_t rbase = (size_t)(wq * 64 + t) * 384 + head * 32;
    float q[32];
    #pragma unroll
    for (int j = 0; j < 4; ++j) {
        bf16x8 qv = *(const bf16x8*)(qkv + rbase + j * 8);
        bf16x8 kv = *(const bf16x8*)(qkv + rbase + 128 + j * 8);
        bf16x8 vv = *(const bf16x8*)(qkv + rbase + 256 + j * 8);
        #pragma unroll
        for (int e = 0; e < 8; ++e) {
            int dd = j * 8 + e;
            q[dd] = (float)qv[e] * 0.17677669529663687f;
            kT[head][dd][t] = (float)kv[e];
            vT[head][dd][t] = (float)vv[e];
        }
    }
    __syncthreads();
    const int wloc = wq & 63;
    const int wh = (wloc >> 3) << 3, wwb = (wloc & 7) << 3;
    int regt = 0;
    if (shift) {
        int hp = wh + (t >> 3), wp = wwb + (t & 7);
        int rh = hp < 56 ? 0 : (hp < 60 ? 1 : 2);
        int rw = wp < 56 ? 0 : (wp < 60 ? 1 : 2);
        regt = rh * 3 + rw;
    }
    const int ti = t >> 3, tj = t & 7;
    float s[64];
    float mx = -1e30f;
    #pragma unroll
    for (int m = 0; m < 64; ++m) {
        float acc = 0.f;
        #pragma unroll
        for (int dd = 0; dd < 32; ++dd) acc += q[dd] * kT[head][dd][m];
        int idx = (ti - (m >> 3) + 7) * 15 + (tj - (m & 7) + 7);
        acc += BF(rp[idx * 4 + head]);
        if (shift) {
            int hp = wh + (m >> 3), wp = wwb + (m & 7);
            int rh = hp < 56 ? 0 : (hp < 60 ? 1 : 2);
            int rw = wp < 56 ? 0 : (wp < 60 ? 1 : 2);
            if (regt != rh * 3 + rw) acc -= 100.f;
        }
        s[m] = acc;
        mx = fmaxf(mx, acc);
    }
    float l = 0.f;
    #pragma unroll
    for (int m = 0; m < 64; ++m) {
        s[m] = expf(s[m] - mx);
        l += s[m];
    }
    const float inv = 1.f / l;
    const size_t obase = (size_t)(wq * 64 + t) * 128 + head * 32;
    #pragma unroll
    for (int j = 0; j < 4; ++j) {
        bf16x8 ov;
        #pragma unroll
        for (int e = 0; e < 8; ++e) {
            int dd = j * 8 + e;
            float a = 0.f;
            #pragma unroll
            for (int m = 0; m < 64; ++m) a += s[m] * vT[head][dd][m];
            ov[e] = (__bf16)(a * inv);
        }
        *(bf16x8*)(outp + obase + j * 8) = ov;
    }
}

// ---------------------------------------------------------------------------
// Fused MLP: LN2 + f1 + GELU + f2 + residual into g (+ bf16 copy to gbf).
// Block = 64 rows, 512 blocks. LDS: Ach 4x[64][36] | buf2 2x[64][36].
// B1/B2 fragments loaded directly from global (L2-resident weights).
// ---------------------------------------------------------------------------
__launch_bounds__(256)
__global__ void mlp_k(float* __restrict__ g, bf16* __restrict__ gbf,
                      const u16* __restrict__ wtu, const bf16* __restrict__ wtb,
                      int d) {
    __shared__ __align__(16) u16 Ach[4 * CH_S];
    __shared__ __align__(16) u16 buf2[2 * CH_S];
    const int tid = threadIdx.x;
    const int wave = tid >> 6, lane = tid & 63;
    const int q = lane >> 4, lr = lane & 15;
    const int wm = (wave >> 1) << 5;   // 0 / 32 (row split)
    const int wn0 = (wave & 1) << 5;   // stage1: 32-hcol split
    const int wn = (wave & 1) << 6;    // stage2: 64-ncol split
    const int bm = blockIdx.x << 6;

    // LN2: thread = (row = tid>>2, qtr = tid&3)
    {
        int row = tid >> 2, qtr = tid & 3;
        const float* gr = g + (size_t)(bm + row) * 128 + qtr * 32;
        float vals[32];
        float s1 = 0.f, s2 = 0.f;
        #pragma unroll
        for (int i = 0; i < 8; ++i) {
            float4 v4 = *(const float4*)(gr + i * 4);
            vals[i * 4] = v4.x; vals[i * 4 + 1] = v4.y;
            vals[i * 4 + 2] = v4.z; vals[i * 4 + 3] = v4.w;
            s1 += v4.x + v4.y + v4.z + v4.w;
            s2 += v4.x * v4.x + v4.y * v4.y + v4.z * v4.z + v4.w * v4.w;
        }
        s1 += __shfl_xor(s1, 1); s1 += __shfl_xor(s1, 2);
        s2 += __shfl_xor(s2, 1); s2 += __shfl_xor(s2, 2);
        float mu = s1 * (1.f / 128.f);
        float var = s2 * (1.f / 128.f) - mu * mu;
        float inv = rsqrtf(var + 1e-5f);
        #pragma unroll
        for (int i = 0; i < 32; ++i) {
            int c = qtr * 32 + i;
            float o = (vals[i] - mu) * inv * BF(wtb[O_N2G + d * 128 + c])
                      + BF(wtb[O_N2B + d * 128 + c]);
            Ach[qtr * CH_S + row * ROW_S + i] = FBu(o);
        }
    }
    __syncthreads();

    const f32x4 zero = {0.f, 0.f, 0.f, 0.f};
    f32x4 acc2[2][4];
    #pragma unroll
    for (int i = 0; i < 2; ++i)
        #pragma unroll
        for (int j = 0; j < 4; ++j) acc2[i][j] = zero;

    for (int h = 0; h < 8; ++h) {
        const u16* B1g = wtu + O_F1W + d * 65536 + h * 8192;
        f32x4 acc1[2][2];
        #pragma unroll
        for (int i = 0; i < 2; ++i) { acc1[i][0] = zero; acc1[i][1] = zero; }
        #pragma unroll
        for (int k0 = 0; k0 < 4; ++k0) {
            bf16x8 af[2], bfr[2];
            #pragma unroll
            for (int t = 0; t < 2; ++t) {
                af[t]  = *(const bf16x8*)(Ach + k0 * CH_S + (wm + (t << 4) + lr) * ROW_S + (q << 3));
                bfr[t] = *(const bf16x8*)(B1g + ((wn0 + (t << 4) + lr) << 7) + (k0 << 5) + (q << 3));
            }
            #pragma unroll
            for (int mt = 0; mt < 2; ++mt)
                #pragma unroll
                for (int nt = 0; nt < 2; ++nt)
                    acc1[mt][nt] = __builtin_amdgcn_mfma_f32_16x16x32_bf16(
                        af[mt], bfr[nt], acc1[mt][nt], 0, 0, 0);
        }
        // GELU -> hidden chunks (padded) in buf2
        #pragma unroll
        for (int nt = 0; nt < 2; ++nt) {
            int c = wn0 + (nt << 4) + lr;
            float hb = BF(wtb[O_F1B + d * 512 + h * 64 + c]);
            #pragma unroll
            for (int mt = 0; mt < 2; ++mt) {
                #pragma unroll
                for (int i = 0; i < 4; ++i) {
                    int r = wm + (mt << 4) + (q << 2) + i;
                    float v = acc1[mt][nt][i] + hb;
                    float ge = 0.5f * v * (1.0f + erff(v * 0.70710678118654752f));
                    buf2[(c >> 5) * CH_S + r * ROW_S + (c & 31)] = FBu(ge);
                }
            }
        }
        __syncthreads();
        // stage 2: direct B2 fragment loads ([128 out][512 K] row-major)
        const u16* B2g = wtu + O_F2W + d * 65536 + h * 64;
        #pragma unroll
        for (int kc = 0; kc < 2; ++kc) {
            bf16x8 ah[2], b2[4];
            #pragma unroll
            for (int t = 0; t < 2; ++t)
                ah[t] = *(const bf16x8*)(buf2 + kc * CH_S + (wm + (t << 4) + lr) * ROW_S + (q << 3));
            #pragma unroll
            for (int t = 0; t < 4; ++t)
                b2[t] = *(const bf16x8*)(B2g + (size_t)(wn + (t << 4) + lr) * 512 + (kc << 5) + (q << 3));
            #pragma unroll
            for (int mt = 0; mt < 2; ++mt)
                #pragma unroll
                for (int nt = 0; nt < 4; ++nt)
                    acc2[mt][nt] = __builtin_amdgcn_mfma_f32_16x16x32_bf16(
                        ah[mt], b2[nt], acc2[mt][nt], 0, 0, 0);
        }
        __syncthreads();
    }
    #pragma unroll
    for (int nt = 0; nt < 4; ++nt) {
        int col = wn + (nt << 4) + lr;
        float bv = BF(wtb[O_F2B + d * 128 + col]);
        #pragma unroll
        for (int mt = 0; mt < 2; ++mt) {
            #pragma unroll
            for (int i = 0; i < 4; ++i) {
                int r = bm + wm + (mt << 4) + (q << 2) + i;
                size_t idx = (size_t)r * 128 + col;
                float nv = g[idx] + acc2[mt][nt][i] + bv;
                g[idx] = nv;
                gbf[idx] = FB(nv);
            }
        }
    }
}

// ---------------------------------------------------------------------------
// Fused fusion chain + LSTM gate -> out. 64-row tiles, 512 blocks (2/CU).
// GEMM operands loaded directly from global (A [M][K], W [N][K]: fragments
// are 16 contiguous bytes). Only the ReLU intermediate lives in LDS
// (padded ROW_S layout -> conflict-free b16 writes and ds_read_b128 reads).
// 2 barriers total instead of ~16 vmcnt(0)+barrier drains.
// ---------------------------------------------------------------------------
__launch_bounds__(256, 2)
__global__ void fuse3_k(const u16* __restrict__ Aloc, const u16* __restrict__ Ag,
                        const u16* __restrict__ wtu, const bf16* __restrict__ wtb,
                        const void* __restrict__ cx, void* __restrict__ out,
                        const void* __restrict__ dtp) {
    __shared__ __align__(16) u16 relb[4 * CH_S];
    const int mode = get_mode(dtp);
    const int tid = threadIdx.x;
    const int wave = tid >> 6, lane = tid & 63;
    const int q = lane >> 4, lr = lane & 15;
    const int wm = (wave >> 1) << 5, wn = (wave & 1) << 6;
    const int bm = blockIdx.x << 6;
    const f32x4 zero = {0.f, 0.f, 0.f, 0.f};
    f32x4 acc1[2][4], acc2[2][4];
    #pragma unroll
    for (int i = 0; i < 2; ++i)
        #pragma unroll
        for (int j = 0; j < 4; ++j) { acc1[i][j] = zero; acc2[i][j] = zero; }

    #pragma unroll
    for (int k0 = 0; k0 < 4; ++k0) {
        bf16x8 al[2], ag[2], blf[4], bgf[4];
        #pragma unroll
        for (int t = 0; t < 2; ++t) {
            size_t off = (size_t)(bm + wm + (t << 4) + lr) * 128 + (k0 << 5) + (q << 3);
            al[t] = *(const bf16x8*)(Aloc + off);
            ag[t] = *(const bf16x8*)(Ag + off);
        }
        #pragma unroll
        for (int t = 0; t < 4; ++t) {
            int woff = ((wn + (t << 4) + lr) << 7) + (k0 << 5) + (q << 3);
            blf[t] = *(const bf16x8*)(wtu + O_LFW + woff);
            bgf[t] = *(const bf16x8*)(wtu + O_GFW + woff);
        }
        #pragma unroll
        for (int mt = 0; mt < 2; ++mt)
            #pragma unroll
            for (int nt = 0; nt < 4; ++nt) {
                acc1[mt][nt] = __builtin_amdgcn_mfma_f32_16x16x32_bf16(
                    al[mt], blf[nt], acc1[mt][nt], 0, 0, 0);
                acc2[mt][nt] = __builtin_amdgcn_mfma_f32_16x16x32_bf16(
                    ag[mt], bgf[nt], acc2[mt][nt], 0, 0, 0);
            }
    }
    // relu((local@lf + lfb) * (g@gf + gfb)) -> padded LDS
    #pragma unroll
    for (int nt = 0; nt < 4; ++nt) {
        int c = wn + (nt << 4) + lr;
        float lfb = BF(wtb[O_LFB + c]);
        float gfb = BF(wtb[O_GFB + c]);
        #pragma unroll
        for (int mt = 0; mt < 2; ++mt) {
            #pragma unroll
            for (int i = 0; i < 4; ++i) {
                int r = wm + (mt << 4) + (q << 2) + i;
                float t1 = acc1[mt][nt][i] + lfb;
                float t2 = acc2[mt][nt][i] + gfb;
                float rel = t1 * t2;
                relb[(c >> 5) * CH_S + r * ROW_S + (c & 31)] = FBu(rel > 0.f ? rel : 0.f);
            }
        }
    }
    __syncthreads();
    f32x4 acc3[2][4];
    #pragma unroll
    for (int i = 0; i < 2; ++i)
        #pragma unroll
        for (int j = 0; j < 4; ++j) acc3[i][j] = zero;
    #pragma unroll
    for (int k0 = 0; k0 < 4; ++k0) {
        bf16x8 ar[2], bff[4];
        #pragma unroll
        for (int t = 0; t < 2; ++t)
            ar[t] = *(const bf16x8*)(relb + k0 * CH_S + (wm + (t << 4) + lr) * ROW_S + (q << 3));
        #pragma unroll
        for (int t = 0; t < 4; ++t)
            bff[t] = *(const bf16x8*)(wtu + O_FFW + ((wn + (t << 4) + lr) << 7) + (k0 << 5) + (q << 3));
        #pragma unroll
        for (int mt = 0; mt < 2; ++mt)
            #pragma unroll
            for (int nt = 0; nt < 4; ++nt)
                acc3[mt][nt] = __builtin_amdgcn_mfma_f32_16x16x32_bf16(
                    ar[mt], bff[nt], acc3[mt][nt], 0, 0, 0);
    }
    // LSTM gating epilogue
    #pragma unroll
    for (int nt = 0; nt < 4; ++nt) {
        int col = wn + (nt << 4) + lr;
        float ffb = BF(wtb[O_FFB + col]);
        #pragma unroll
        for (int mt = 0; mt < 2; ++mt) {
            #pragma unroll
            for (int i = 0; i < 4; ++i) {
                int r = bm + wm + (mt << 4) + (q << 2) + i;
                size_t idx = (size_t)r * 128 + col;
                float v = acc3[mt][nt][i] + ffb;
                float gate = 1.f / (1.f + expf(-v));
                float cell = tanhf(v);
                float cy = gate * (LD(cx, idx, mode) + cell);
                float hy = gate * tanhf(cy);
                if (mode) ((float*)out)[idx] = hy;
                else      ((bf16*)out)[idx] = FB(hy);
            }
        }
    }
}

// ---------------------------------------------------------------------------
// Deformable conv1d local branch; bf16 out in (B,C,L) layout.
// ---------------------------------------------------------------------------
__launch_bounds__(256)
__global__ void deform_k(const void* __restrict__ xt, const bf16* __restrict__ wtb,
                         bf16* __restrict__ outL) {
    __shared__ __align__(16) u16 ot[128 * 72];
    __shared__ int s_fp[192], s_cp[192];
    __shared__ float s_al[192], s_mk[192];
    const int mode = get_mode(xt);
    const int tid = threadIdx.x;
    const int wave = tid >> 6, lane = tid & 63;
    const int b = blockIdx.x >> 6;
    const int l0 = (blockIdx.x & 63) << 6;
    float wo[3][3][2], wmk[3][3][2];
    #pragma unroll
    for (int k = 0; k < 3; ++k)
        #pragma unroll
        for (int j = 0; j < 3; ++j) {
            wo[k][j][0]  = BF(wtb[O_OW + (k * 128 + lane) * 3 + j]);
            wo[k][j][1]  = BF(wtb[O_OW + (k * 128 + lane + 64) * 3 + j]);
            wmk[k][j][0] = BF(wtb[O_MW + (k * 128 + lane) * 3 + j]);
            wmk[k][j][1] = BF(wtb[O_MW + (k * 128 + lane + 64) * 3 + j]);
        }
    for (int il = 0; il < 16; ++il) {
        int l_loc = wave * 16 + il;
        int l = l0 + l_loc;
        float a6[6] = {};
        #pragma unroll
        for (int j = 0; j < 3; ++j) {
            int row = l + j - 1;
            if (row >= 0 && row < 4096) {
                size_t base = ((size_t)(b << 12) + row) * 128;
                float x0 = LD(xt, base + lane, mode);
                float x1 = LD(xt, base + lane + 64, mode);
                #pragma unroll
                for (int k = 0; k < 3; ++k) {
                    a6[k]     += x0 * wo[k][j][0]  + x1 * wo[k][j][1];
                    a6[3 + k] += x0 * wmk[k][j][0] + x1 * wmk[k][j][1];
                }
            }
        }
        #pragma unroll
        for (int off = 32; off > 0; off >>= 1)
            #pragma unroll
            for (int k = 0; k < 6; ++k) a6[k] += __shfl_down(a6[k], off);
        if (lane == 0) {
            #pragma unroll
            for (int k = 0; k < 3; ++k) {
                float off = a6[k] + BF(wtb[O_OB + k]);
                float pos = fminf(fmaxf((float)l + off, 0.f), 4095.f);
                float fpf = floorf(pos);
                int fp = (int)fpf;
                int cp = fp + 1 > 4095 ? 4095 : fp + 1;
                s_fp[l_loc * 3 + k] = fp;
                s_cp[l_loc * 3 + k] = cp;
                s_al[l_loc * 3 + k] = pos - fpf;
                float mv = a6[3 + k] + BF(wtb[O_MB + k]);
                s_mk[l_loc * 3 + k] = 1.f / (1.f + expf(-mv));
            }
        }
    }
    __syncthreads();
    {
        int c = tid & 127, lh = tid >> 7;
        for (int it = 0; it < 32; ++it) {
            int l_loc = lh * 32 + it;
            float o = 0.f;
            #pragma unroll
            for (int k = 0; k < 3; ++k) {
                int fp = s_fp[l_loc * 3 + k];
                int cp = s_cp[l_loc * 3 + k];
                float al = s_al[l_loc * 3 + k];
                float mk = s_mk[l_loc * 3 + k];
                float xf = LD(xt, ((size_t)(b << 12) + fp) * 128 + c, mode);
                float xc = LD(xt, ((size_t)(b << 12) + cp) * 128 + c, mode);
                o += (xf * (1.f - al) + xc * al) * mk;
            }
            ot[c * 72 + l_loc] = FBu(o);
        }
    }
    __syncthreads();
    #pragma unroll
    for (int pass = 0; pass < 4; ++pass) {
        int cc = pass * 32 + (tid >> 3);
        int oo = tid & 7;
        const uint4 v = *(const uint4*)(ot + cc * 72 + oo * 8);
        *(uint4*)(outL + (size_t)b * 524288 + (size_t)cc * 4096 + l0 + oo * 8) = v;
    }
}

extern "C" void kernel_launch(void* const* d_in, const int* in_sizes, int n_in,
                              void* d_out, int out_size, void* d_ws, size_t ws_size,
                              hipStream_t stream) {
    (void)out_size; (void)ws_size;
    int I[28] = {0,1,2,3,4,5,6,7,8,9,10,11,12,13,14,15,16,17,18,19,20,21,22,23,24,25,26,27};
    if (n_in >= 28 && in_sizes[7] != 98304 && in_sizes[23] == 98304 && in_sizes[26] == 1800) {
        int alt[28] = {27, 9, 0, 25, 24, 15, 14, 23, 22, 26, 21, 20, 17, 16,
                       2, 1, 4, 3, 19, 18, 13, 12, 11, 10, 8, 7, 6, 5};
        for (int i = 0; i < 28; ++i) I[i] = alt[i];
    }
    const void* xt = d_in[I[0]];
    const void* hx = d_in[I[1]];
    const void* cx = d_in[I[2]];

    char* wsb = (char*)d_ws;
    float* g    = (float*)wsb;                    // fp32 residual [0,16M)
    u16*   Abf  = (u16*)(wsb + 16777216);         // bf16(g)
    u16*   Bbf  = (u16*)(wsb + 25165824);         // Xcat / qkv
    u16*   Cbf  = (u16*)(wsb + 50331648);         // attn-out / local
    bf16*  wtb  = (bf16*)(wsb + 58720256);
    u16*   wtu  = (u16*)wtb;

    Prep p;
    PrepT descs[29] = {
        {d_in[I[3]],  0,     256, 128, O_REDW},
        {d_in[I[7]],  0,     128, 384, O_QKVW},
        {d_in[I[7]],  49152, 128, 384, O_QKVW + 49152},
        {d_in[I[10]], 0,     128, 128, O_PW},
        {d_in[I[10]], 16384, 128, 128, O_PW + 16384},
        {d_in[I[14]], 0,     128, 512, O_F1W},
        {d_in[I[14]], 65536, 128, 512, O_F1W + 65536},
        {d_in[I[16]], 0,     512, 128, O_F2W},
        {d_in[I[16]], 65536, 512, 128, O_F2W + 65536},
        {d_in[I[22]], 0,     128, 128, O_LFW},
        {d_in[I[24]], 0,     128, 128, O_GFW},
        {d_in[I[26]], 0,     128, 128, O_FFW},
        {d_in[I[4]],  0,  128, 0, O_REDB},
        {d_in[I[8]],  0,  768, 0, O_QKVB},
        {d_in[I[11]], 0,  256, 0, O_PB},
        {d_in[I[15]], 0, 1024, 0, O_F1B},
        {d_in[I[17]], 0,  256, 0, O_F2B},
        {d_in[I[23]], 0,  128, 0, O_LFB},
        {d_in[I[25]], 0,  128, 0, O_GFB},
        {d_in[I[27]], 0,  128, 0, O_FFB},
        {d_in[I[9]],  0, 1800, 0, O_RP},
        {d_in[I[5]],  0,  256, 0, O_N1G},
        {d_in[I[6]],  0,  256, 0, O_N1B},
        {d_in[I[12]], 0,  256, 0, O_N2G},
        {d_in[I[13]], 0,  256, 0, O_N2B},
        {d_in[I[18]], 0, 1152, 0, O_OW},
        {d_in[I[19]], 0,    3, 0, O_OB},
        {d_in[I[20]], 0, 1152, 0, O_MW},
        {d_in[I[21]], 0,    3, 0, O_MB},
    };
    int cum = 0;
    for (int i = 0; i < 29; ++i) {
        p.d[i] = descs[i];
        p.start[i] = cum;
        cum += (descs[i].N > 0) ? descs[i].K * descs[i].N : descs[i].K;
    }
    p.start[29] = cum;

    prep_k<<<(cum + 255) / 256, 256, 0, stream>>>(p, wtb, xt);
    xcat_k<<<1024, 256, 0, stream>>>(xt, hx, Bbf);

    // g = Xcat @ red_w + red_b (fp32)
    gemm_mfma<5><<<dim3(1, 256), 256, 0, stream>>>(Bbf, wtu + O_REDW, wtb + O_REDB,
                                                   nullptr, g, 32768, 128, 256, 0);

    for (int d = 0; d < 2; ++d) {
        int shift = d ? 4 : 0;
        qkvln_k<<<512, 256, 0, stream>>>(g, wtu, wtb, Bbf, d, shift);
        attn_k<<<512, 256, 0, stream>>>(Bbf, wtb + O_RP + d * 900, Cbf, shift);
        gemm_mfma<3><<<dim3(1, 256), 256, 0, stream>>>(Cbf, wtu + O_PW + d * 16384,
                                                       wtb + O_PB + d * 128, nullptr, g,
                                                       32768, 128, 128, shift);
        mlp_k<<<512, 256, 0, stream>>>(g, (bf16*)Abf, wtu, wtb, d);
    }

    // local branch -> Cbf (B,C,L)
    deform_k<<<512, 256, 0, stream>>>(xt, wtb, (bf16*)Cbf);
    // fused fusion chain + LSTM -> out
    fuse3_k<<<512, 256, 0, stream>>>(Cbf, Abf, wtu, wtb, cx, d_out, xt);
}

// Round 2
// 438.749 us; speedup vs baseline: 1.1322x; 1.1322x over previous
//
#include <hip/hip_runtime.h>
#include <hip/hip_bf16.h>
#include <math.h>

typedef __hip_bfloat16 bf16;
typedef unsigned short u16;
#define BF(x) __bfloat162float(x)
static __device__ __forceinline__ bf16 FB(float x) { return __float2bfloat16(x); }
static __device__ __forceinline__ u16 FBu(float x) {
    bf16 b = __float2bfloat16(x);
    return *(u16*)&b;
}

typedef __attribute__((ext_vector_type(4))) float f32x4;
typedef __attribute__((ext_vector_type(8))) __bf16 bf16x8;

// Problem: B=8, H=W=64, C=128, L=4096, NH=4, HD=32, WIN=8, N=64, NW=64, M=32768.

// Wt (prepped bf16 weights) element offsets
#define O_REDW 0
#define O_QKVW 32768
#define O_PW   131072
#define O_F1W  163840
#define O_F2W  294912
#define O_LFW  425984
#define O_GFW  442368
#define O_FFW  458752
#define O_REDB 475136
#define O_QKVB 475264
#define O_PB   476032
#define O_F1B  476288
#define O_F2B  477312
#define O_LFB  477568
#define O_GFB  477696
#define O_FFB  477824
#define O_RP   477952
#define O_N1G  479752
#define O_N1B  480008
#define O_N2G  480264
#define O_N2B  480520
#define O_OW   480776
#define O_OB   481928
#define O_MW   481931
#define O_MB   483083

// Padded LDS tile geometry for VALU-written A-tiles (kills 16-way conflicts):
// row stride 36 u16 (72 B = 18 banks), chunk stride 2320 u16.
#define ROW_S 36
#define CH_S  2320

// Runtime input-dtype detection from xt (N(0,1) data). 0 = bf16, 1 = fp32.
__device__ __forceinline__ int get_mode(const void* xt) {
    const unsigned* w = (const unsigned*)xt;
    int zlo = 0, inband = 0;
    #pragma unroll
    for (int i = 0; i < 32; ++i) {
        unsigned lo = w[i] & 0xFFFFu;
        int e = (int)((lo >> 7) & 0xFF);
        zlo += (lo == 0u || lo == 0x8000u);
        inband += (e >= 100 && e <= 140);
    }
    if (zlo >= 29) return 1;
    return (inband >= 20) ? 0 : 1;
}

__device__ __forceinline__ float LD(const void* p, size_t i, int mode) {
    return mode ? ((const float*)p)[i] : BF(((const bf16*)p)[i]);
}

// async global->LDS, 16 bytes per lane
__device__ __forceinline__ void async16(const u16* g, u16* l) {
    __builtin_amdgcn_global_load_lds(
        (const __attribute__((address_space(1))) unsigned int*)g,
        (__attribute__((address_space(3))) unsigned int*)l, 16, 0, 0);
}

// ---------------------------------------------------------------------------
// Prep: transpose weights to [N][K] bf16 + convert params.
// ---------------------------------------------------------------------------
struct PrepT { const void* src; int srcOff, K, N, dstOff; };
struct Prep { PrepT d[29]; int start[30]; };

__global__ void prep_k(Prep p, bf16* __restrict__ dst, const void* __restrict__ dtp) {
    const int mode = get_mode(dtp);
    int i = blockIdx.x * 256 + threadIdx.x;
    if (i >= p.start[29]) return;
    int s = 0;
    while (p.start[s + 1] <= i) ++s;
    int e = i - p.start[s];
    float v;
    if (p.d[s].N > 0) {
        int n = e / p.d[s].K, k = e % p.d[s].K;
        v = LD(p.d[s].src, (size_t)p.d[s].srcOff + (size_t)k * p.d[s].N + n, mode);
    } else {
        v = LD(p.d[s].src, (size_t)p.d[s].srcOff + e, mode);
    }
    dst[p.d[s].dstOff + e] = FB(v);
}

// Vectorized concat: X[32768][256] = bf16([xt | hx]).  Grid-stride.
__launch_bounds__(256)
__global__ void xcat_k(const void* __restrict__ xt, const void* __restrict__ hx,
                       u16* __restrict__ X) {
    const int mode = get_mode(xt);
    const int total = 32768 * 32;            // groups of 8 elements
    for (int gidx = blockIdx.x * 256 + threadIdx.x; gidx < total;
         gidx += gridDim.x * 256) {
        int r = gidx >> 5, gi = gidx & 31;
        const void* src = (gi < 16) ? xt : hx;
        int c = (gi & 15) << 3;
        u16 outv[8];
        if (mode) {
            const float* s = (const float*)src + (size_t)r * 128 + c;
            float4 a = *(const float4*)s;
            float4 b = *(const float4*)(s + 4);
            outv[0] = FBu(a.x); outv[1] = FBu(a.y); outv[2] = FBu(a.z); outv[3] = FBu(a.w);
            outv[4] = FBu(b.x); outv[5] = FBu(b.y); outv[6] = FBu(b.z); outv[7] = FBu(b.w);
        } else {
            *(uint4*)outv = *(const uint4*)((const u16*)src + (size_t)r * 128 + c);
        }
        *(uint4*)(X + (size_t)r * 256 + (gi << 3)) = *(const uint4*)outv;
    }
}

// ---------------------------------------------------------------------------
// MFMA GEMM, 64x128 tile (grid (1,512) -> 2 blocks/CU), BK=32, double-
// buffered LDS staging: stage(k+1) is issued BEFORE compute(k), one barrier
// per K-step (T3 minimum-2-phase). EPI 3: window-reverse/roll scatter-add
// into outf. 5: fp32 store.
// ---------------------------------------------------------------------------
template <int EPI>
__launch_bounds__(256)
__global__ void gemm_mfma(const u16* __restrict__ A, const u16* __restrict__ Bt,
                          const bf16* __restrict__ bias, bf16* __restrict__ outb,
                          float* __restrict__ outf, int M, int N, int K, int shift) {
    __shared__ __align__(16) u16 Als[2][2048];   // 64 rows x 32 k
    __shared__ __align__(16) u16 Bls[2][4096];   // 128 rows x 32 k
    const int tid = threadIdx.x;
    const int wave = tid >> 6, lane = tid & 63;
    const int q = lane >> 4, lr = lane & 15;
    const int wm = (wave >> 1) << 5, wn = (wave & 1) << 6;
    const int bm = blockIdx.y << 6, bn = blockIdx.x << 7;
    const f32x4 zero = {0.f, 0.f, 0.f, 0.f};
    f32x4 acc[2][4];
    #pragma unroll
    for (int i = 0; i < 2; ++i)
        #pragma unroll
        for (int j = 0; j < 4; ++j) acc[i][j] = zero;

    const int nk = K >> 5;
    {   // prologue: stage k-tile 0 into buffer 0
        int c = tid;
        async16(A + (size_t)(bm + (c >> 2)) * K + ((c & 3) << 3), Als[0] + (c << 3));
        #pragma unroll
        for (int c2 = tid; c2 < 512; c2 += 256)
            async16(Bt + (size_t)(bn + (c2 >> 2)) * K + ((c2 & 3) << 3), Bls[0] + (c2 << 3));
    }
    __syncthreads();

    for (int i = 0; i < nk; ++i) {
        const int cur = i & 1, nxt = cur ^ 1;
        if (i + 1 < nk) {                      // issue next-tile stage FIRST
            int k1 = (i + 1) << 5;
            int c = tid;
            async16(A + (size_t)(bm + (c >> 2)) * K + k1 + ((c & 3) << 3), Als[nxt] + (c << 3));
            #pragma unroll
            for (int c2 = tid; c2 < 512; c2 += 256)
                async16(Bt + (size_t)(bn + (c2 >> 2)) * K + k1 + ((c2 & 3) << 3), Bls[nxt] + (c2 << 3));
        }
        bf16x8 af[2], bfr[4];
        #pragma unroll
        for (int t = 0; t < 2; ++t)
            af[t] = *(const bf16x8*)(Als[cur] + ((wm + (t << 4) + lr) << 5) + (q << 3));
        #pragma unroll
        for (int t = 0; t < 4; ++t)
            bfr[t] = *(const bf16x8*)(Bls[cur] + ((wn + (t << 4) + lr) << 5) + (q << 3));
        #pragma unroll
        for (int mt = 0; mt < 2; ++mt)
            #pragma unroll
            for (int nt = 0; nt < 4; ++nt)
                acc[mt][nt] = __builtin_amdgcn_mfma_f32_16x16x32_bf16(
                    af[mt], bfr[nt], acc[mt][nt], 0, 0, 0);
        __syncthreads();                        // drains next-tile stage
    }

    #pragma unroll
    for (int nt = 0; nt < 4; ++nt) {
        int col = bn + wn + (nt << 4) + lr;
        float bv = BF(bias[col]);
        #pragma unroll
        for (int mt = 0; mt < 2; ++mt) {
            int row0 = bm + wm + (mt << 4) + (q << 2);
            #pragma unroll
            for (int i = 0; i < 4; ++i) {
                int r = row0 + i;
                float v = acc[mt][nt][i] + bv;
                size_t idx = (size_t)r * N + col;
                if (EPI == 0) {
                    outb[idx] = FB(v);
                } else if (EPI == 3) {
                    int b = r >> 12, rem = r & 4095;
                    int wi = rem >> 6, n = rem & 63;
                    int hp = ((wi >> 3) << 3) + (n >> 3);
                    int wp = ((wi & 7) << 3) + (n & 7);
                    int h = (hp + shift) & 63, w = (wp + shift) & 63;
                    outf[((size_t)((b << 12) + (h << 6) + w)) * 128 + col] += v;
                } else if (EPI == 5) {
                    outf[idx] = v;
                }
            }
        }
    }
}

// ---------------------------------------------------------------------------
// Fused LN1 (+roll+window gather) + QKV GEMM. Block = 64 windowed rows,
// 512 blocks. LDS: Ach 4x[64][36] padded | Bb double-buffered 2x16KB.
// Pipeline: 6 half-K sub-tiles (nc x khalf); stage(s+1) issued before
// compute(s); stage(0) issued before the LN so it hides under LN's loads.
// ---------------------------------------------------------------------------
__launch_bounds__(256)
__global__ void qkvln_k(const float* __restrict__ g, const u16* __restrict__ wtu,
                        const bf16* __restrict__ wtb, u16* __restrict__ qkv,
                        int d, int shift) {
    __shared__ __align__(16) u16 Ach[4 * CH_S];
    __shared__ __align__(16) u16 Bb[2][8192];
    const int tid = threadIdx.x;
    const int wave = tid >> 6, lane = tid & 63;
    const int q = lane >> 4, lr = lane & 15;
    const int wm = (wave >> 1) << 5, wn = (wave & 1) << 6;
    const int bm = blockIdx.x << 6;
    const u16* Wq = wtu + O_QKVW + d * 49152;

    // prologue stage: sub-tile 0 (nc=0, khalf=0) into Bb[0]
    #pragma unroll
    for (int i = tid; i < 1024; i += 256) {
        int kc = i >> 9, c = i & 511;
        async16(Wq + (size_t)(c >> 2) * 128 + (kc << 5) + ((c & 3) << 3),
                Bb[0] + (kc << 12) + (c << 3));
    }

    // LN1 with inverse-roll gather: thread = (row = tid>>2, qtr = tid&3)
    {
        int row = tid >> 2, qtr = tid & 3;
        int r = bm + row;
        int b = r >> 12, rem = r & 4095;
        int wi = rem >> 6, n = rem & 63;
        int hp = ((wi >> 3) << 3) + (n >> 3);
        int wp = ((wi & 7) << 3) + (n & 7);
        int h = (hp + shift) & 63, w = (wp + shift) & 63;
        int src = (b << 12) + (h << 6) + w;
        const float* gr = g + (size_t)src * 128 + qtr * 32;
        float vals[32];
        float s1 = 0.f, s2 = 0.f;
        #pragma unroll
        for (int i = 0; i < 8; ++i) {
            float4 v4 = *(const float4*)(gr + i * 4);
            vals[i * 4] = v4.x; vals[i * 4 + 1] = v4.y;
            vals[i * 4 + 2] = v4.z; vals[i * 4 + 3] = v4.w;
            s1 += v4.x + v4.y + v4.z + v4.w;
            s2 += v4.x * v4.x + v4.y * v4.y + v4.z * v4.z + v4.w * v4.w;
        }
        s1 += __shfl_xor(s1, 1); s1 += __shfl_xor(s1, 2);
        s2 += __shfl_xor(s2, 1); s2 += __shfl_xor(s2, 2);
        float mu = s1 * (1.f / 128.f);
        float var = s2 * (1.f / 128.f) - mu * mu;
        float inv = rsqrtf(var + 1e-5f);
        #pragma unroll
        for (int i = 0; i < 32; ++i) {
            int c = qtr * 32 + i;
            float o = (vals[i] - mu) * inv * BF(wtb[O_N1G + d * 128 + c])
                      + BF(wtb[O_N1B + d * 128 + c]);
            Ach[qtr * CH_S + row * ROW_S + i] = FBu(o);
        }
    }
    __syncthreads();   // drains stage(0); Ach visible

    const f32x4 zero = {0.f, 0.f, 0.f, 0.f};
    f32x4 acc[2][4];
    for (int s = 0; s < 6; ++s) {
        const int nc = s >> 1, kh = s & 1, cur = s & 1 ? (s & 1) : (s & 1);
        const int bsel = s & 1;
        if (s < 5) {   // issue next sub-tile stage first
            int t = s + 1, nct = t >> 1, kht = t & 1;
            const u16* Bg = Wq + nct * 16384;
            #pragma unroll
            for (int i = tid; i < 1024; i += 256) {
                int kc = i >> 9, c = i & 511;
                async16(Bg + (size_t)(c >> 2) * 128 + (kht << 6) + (kc << 5) + ((c & 3) << 3),
                        Bb[t & 1] + (kc << 12) + (c << 3));
            }
        }
        if (kh == 0) {
            #pragma unroll
            for (int i = 0; i < 2; ++i)
                #pragma unroll
                for (int j = 0; j < 4; ++j) acc[i][j] = zero;
        }
        #pragma unroll
        for (int kc = 0; kc < 2; ++kc) {
            bf16x8 af[2], bfr[4];
            #pragma unroll
            for (int t = 0; t < 2; ++t)
                af[t] = *(const bf16x8*)(Ach + (2 * kh + kc) * CH_S + (wm + (t << 4) + lr) * ROW_S + (q << 3));
            #pragma unroll
            for (int t = 0; t < 4; ++t)
                bfr[t] = *(const bf16x8*)(Bb[bsel] + (kc << 12) + ((wn + (t << 4) + lr) << 5) + (q << 3));
            #pragma unroll
            for (int mt = 0; mt < 2; ++mt)
                #pragma unroll
                for (int nt = 0; nt < 4; ++nt)
                    acc[mt][nt] = __builtin_amdgcn_mfma_f32_16x16x32_bf16(
                        af[mt], bfr[nt], acc[mt][nt], 0, 0, 0);
        }
        if (kh == 1) {   // epilogue for this nc
            #pragma unroll
            for (int nt = 0; nt < 4; ++nt) {
                int col = wn + (nt << 4) + lr;
                float bv = BF(wtb[O_QKVB + d * 384 + nc * 128 + col]);
                #pragma unroll
                for (int mt = 0; mt < 2; ++mt) {
                    #pragma unroll
                    for (int i = 0; i < 4; ++i) {
                        int r = bm + wm + (mt << 4) + (q << 2) + i;
                        qkv[(size_t)r * 384 + nc * 128 + col] = FBu(acc[mt][nt][i] + bv);
                    }
                }
            }
        }
        if (s < 5) __syncthreads();   // drains stage(s+1); frees Bb[bsel]
    }
}

// ---------------------------------------------------------------------------
// Windowed attention: block = one window (4 heads = 4 waves).
// ---------------------------------------------------------------------------
__launch_bounds__(256)
__global__ void attn_k(const u16* __restrict__ qkv, const bf16* __restrict__ rp,
                       u16* __restrict__ outp, int shift) {
    __shared__ float kT[4][32][64];
    __shared__ float vT[4][32][64];
    const int wq = blockIdx.x;
    const int head = threadIdx.x >> 6;
    const int t = threadIdx.x & 63;
    const size_t rbase = (size_t)(wq * 64 + t) * 384 + head * 32;
    float q[32];
    #pragma unroll
    for (int j = 0; j < 4; ++j) {
        bf16x8 qv = *(const bf16x8*)(qkv + rbase + j * 8);
        bf16x8 kv = *(const bf16x8*)(qkv + rbase + 128 + j * 8);
        bf16x8 vv = *(const bf16x8*)(qkv + rbase + 256 + j * 8);
        #pragma unroll
        for (int e = 0; e < 8; ++e) {
            int dd = j * 8 + e;
            q[dd] = (float)qv[e] * 0.17677669529663687f;
            kT[head][dd][t] = (float)kv[e];
            vT[head][dd][t] = (float)vv[e];
        }
    }
    __syncthreads();
    const int wloc = wq & 63;
    const int wh = (wloc >> 3) << 3, wwb = (wloc & 7) << 3;
    int regt = 0;
    if (shift) {
        int hp = wh + (t >> 3), wp = wwb + (t & 7);
        int rh = hp < 56 ? 0 : (hp < 60 ? 1 : 2);
        int rw = wp < 56 ? 0 : (wp < 60 ? 1 : 2);
        regt = rh * 3 + rw;
    }
    const int ti = t >> 3, tj = t & 7;
    float s[64];
    float mx = -1e30f;
    #pragma unroll
    for (int m = 0; m < 64; ++m) {
        float acc = 0.f;
        #pragma unroll
        for (int dd = 0; dd < 32; ++dd) acc += q[dd] * kT[head][dd][m];
        int idx = (ti - (m >> 3) + 7) * 15 + (tj - (m & 7) + 7);
        acc += BF(rp[idx * 4 + head]);
        if (shift) {
            int hp = wh + (m >> 3), wp = wwb + (m & 7);
            int rh = hp < 56 ? 0 : (hp < 60 ? 1 : 2);
            int rw = wp < 56 ? 0 : (wp < 60 ? 1 : 2);
            if (regt != rh * 3 + rw) acc -= 100.f;
        }
        s[m] = acc;
        mx = fmaxf(mx, acc);
    }
    float l = 0.f;
    #pragma unroll
    for (int m = 0; m < 64; ++m) {
        s[m] = expf(s[m] - mx);
        l += s[m];
    }
    const float inv = 1.f / l;
    const size_t obase = (size_t)(wq * 64 + t) * 128 + head * 32;
    #pragma unroll
    for (int j = 0; j < 4; ++j) {
        bf16x8 ov;
        #pragma unroll
        for (int e = 0; e < 8; ++e) {
            int dd = j * 8 + e;
            float a = 0.f;
            #pragma unroll
            for (int m = 0; m < 64; ++m) a += s[m] * vT[head][dd][m];
            ov[e] = (__bf16)(a * inv);
        }
        *(bf16x8*)(outp + obase + j * 8) = ov;
    }
}

// ---------------------------------------------------------------------------
// Fused MLP: LN2 + f1 + GELU + f2 + residual into g (+ bf16 copy to gbf).
// Block = 64 rows, 512 blocks. LDS: Ach | bufB1 16KB | bufB2 16KB | buf2.
// Pipeline: stage B1(0) before LN; per h: issue B2(h), compute MFMA1+GELU,
// barrier, issue B1(h+1), compute MFMA2, barrier. 2 barriers/h (was 4),
// stage latency hidden under compute.
// ---------------------------------------------------------------------------
__launch_bounds__(256)
__global__ void mlp_k(float* __restrict__ g, bf16* __restrict__ gbf,
                      const u16* __restrict__ wtu, const bf16* __restrict__ wtb,
                      int d) {
    __shared__ __align__(16) u16 Ach[4 * CH_S];
    __shared__ __align__(16) u16 bufB1[8192];
    __shared__ __align__(16) u16 bufB2[8192];
    __shared__ __align__(16) u16 buf2[2 * CH_S];
    const int tid = threadIdx.x;
    const int wave = tid >> 6, lane = tid & 63;
    const int q = lane >> 4, lr = lane & 15;
    const int wm = (wave >> 1) << 5;   // 0 / 32 (row split)
    const int wn0 = (wave & 1) << 5;   // stage1: 32-hcol split
    const int wn = (wave & 1) << 6;    // stage2: 64-ncol split
    const int bm = blockIdx.x << 6;

    // prologue stage: B1 chunk h=0 (hides under LN's global loads)
    {
        const u16* B1g = wtu + O_F1W + d * 65536;
        #pragma unroll
        for (int i = tid; i < 1024; i += 256) {
            int kc = i >> 8, c = i & 255;
            async16(B1g + (c >> 2) * 128 + (kc << 5) + ((c & 3) << 3),
                    bufB1 + (kc << 11) + (c << 3));
        }
    }

    // LN2: thread = (row = tid>>2, qtr = tid&3)
    {
        int row = tid >> 2, qtr = tid & 3;
        const float* gr = g + (size_t)(bm + row) * 128 + qtr * 32;
        float vals[32];
        float s1 = 0.f, s2 = 0.f;
        #pragma unroll
        for (int i = 0; i < 8; ++i) {
            float4 v4 = *(const float4*)(gr + i * 4);
            vals[i * 4] = v4.x; vals[i * 4 + 1] = v4.y;
            vals[i * 4 + 2] = v4.z; vals[i * 4 + 3] = v4.w;
            s1 += v4.x + v4.y + v4.z + v4.w;
            s2 += v4.x * v4.x + v4.y * v4.y + v4.z * v4.z + v4.w * v4.w;
        }
        s1 += __shfl_xor(s1, 1); s1 += __shfl_xor(s1, 2);
        s2 += __shfl_xor(s2, 1); s2 += __shfl_xor(s2, 2);
        float mu = s1 * (1.f / 128.f);
        float var = s2 * (1.f / 128.f) - mu * mu;
        float inv = rsqrtf(var + 1e-5f);
        #pragma unroll
        for (int i = 0; i < 32; ++i) {
            int c = qtr * 32 + i;
            float o = (vals[i] - mu) * inv * BF(wtb[O_N2G + d * 128 + c])
                      + BF(wtb[O_N2B + d * 128 + c]);
            Ach[qtr * CH_S + row * ROW_S + i] = FBu(o);
        }
    }
    __syncthreads();   // drains B1(0); Ach visible

    const f32x4 zero = {0.f, 0.f, 0.f, 0.f};
    f32x4 acc2[2][4];
    #pragma unroll
    for (int i = 0; i < 2; ++i)
        #pragma unroll
        for (int j = 0; j < 4; ++j) acc2[i][j] = zero;

    for (int h = 0; h < 8; ++h) {
        // issue B2(h) stage first (hides under MFMA1 + GELU)
        {
            const u16* B2g = wtu + O_F2W + d * 65536 + h * 64;
            #pragma unroll
            for (int i = tid; i < 1024; i += 256) {
                int kc = i >> 9, c = i & 511;
                async16(B2g + (size_t)(c >> 2) * 512 + (kc << 5) + ((c & 3) << 3),
                        bufB2 + (kc << 12) + (c << 3));
            }
        }
        // MFMA1 from Ach x bufB1 (B1(h), ready from previous barrier)
        f32x4 acc1[2][2];
        #pragma unroll
        for (int i = 0; i < 2; ++i) { acc1[i][0] = zero; acc1[i][1] = zero; }
        #pragma unroll
        for (int k0 = 0; k0 < 4; ++k0) {
            bf16x8 af[2], bfr[2];
            #pragma unroll
            for (int t = 0; t < 2; ++t) {
                af[t]  = *(const bf16x8*)(Ach + k0 * CH_S + (wm + (t << 4) + lr) * ROW_S + (q << 3));
                bfr[t] = *(const bf16x8*)(bufB1 + (k0 << 11) + ((wn0 + (t << 4) + lr) << 5) + (q << 3));
            }
            #pragma unroll
            for (int mt = 0; mt < 2; ++mt)
                #pragma unroll
                for (int nt = 0; nt < 2; ++nt)
                    acc1[mt][nt] = __builtin_amdgcn_mfma_f32_16x16x32_bf16(
                        af[mt], bfr[nt], acc1[mt][nt], 0, 0, 0);
        }
        // GELU -> hidden chunks (padded) in buf2
        #pragma unroll
        for (int nt = 0; nt < 2; ++nt) {
            int c = wn0 + (nt << 4) + lr;
            float hb = BF(wtb[O_F1B + d * 512 + h * 64 + c]);
            #pragma unroll
            for (int mt = 0; mt < 2; ++mt) {
                #pragma unroll
                for (int i = 0; i < 4; ++i) {
                    int r = wm + (mt << 4) + (q << 2) + i;
                    float v = acc1[mt][nt][i] + hb;
                    float ge = 0.5f * v * (1.0f + erff(v * 0.70710678118654752f));
                    buf2[(c >> 5) * CH_S + r * ROW_S + (c & 31)] = FBu(ge);
                }
            }
        }
        __syncthreads();   // drains B2(h); buf2 visible; bufB1 free
        // issue B1(h+1) stage (hides under MFMA2)
        if (h < 7) {
            const u16* B1g = wtu + O_F1W + d * 65536 + (h + 1) * 8192;
            #pragma unroll
            for (int i = tid; i < 1024; i += 256) {
                int kc = i >> 8, c = i & 255;
                async16(B1g + (c >> 2) * 128 + (kc << 5) + ((c & 3) << 3),
                        bufB1 + (kc << 11) + (c << 3));
            }
        }
        // MFMA2 from buf2 x bufB2
        #pragma unroll
        for (int kc = 0; kc < 2; ++kc) {
            bf16x8 ah[2], b2[4];
            #pragma unroll
            for (int t = 0; t < 2; ++t)
                ah[t] = *(const bf16x8*)(buf2 + kc * CH_S + (wm + (t << 4) + lr) * ROW_S + (q << 3));
            #pragma unroll
            for (int t = 0; t < 4; ++t)
                b2[t] = *(const bf16x8*)(bufB2 + (kc << 12) + ((wn + (t << 4) + lr) << 5) + (q << 3));
            #pragma unroll
            for (int mt = 0; mt < 2; ++mt)
                #pragma unroll
                for (int nt = 0; nt < 4; ++nt)
                    acc2[mt][nt] = __builtin_amdgcn_mfma_f32_16x16x32_bf16(
                        ah[mt], b2[nt], acc2[mt][nt], 0, 0, 0);
        }
        __syncthreads();   // drains B1(h+1); bufB2/buf2 free
    }
    #pragma unroll
    for (int nt = 0; nt < 4; ++nt) {
        int col = wn + (nt << 4) + lr;
        float bv = BF(wtb[O_F2B + d * 128 + col]);
        #pragma unroll
        for (int mt = 0; mt < 2; ++mt) {
            #pragma unroll
            for (int i = 0; i < 4; ++i) {
                int r = bm + wm + (mt << 4) + (q << 2) + i;
                size_t idx = (size_t)r * 128 + col;
                float nv = g[idx] + acc2[mt][nt][i] + bv;
                g[idx] = nv;
                gbf[idx] = FB(nv);
            }
        }
    }
}

// ---------------------------------------------------------------------------
// Fused fusion chain + LSTM gate -> out. 64-row tiles, 512 blocks (2/CU).
// GEMM operands loaded directly from global (A [M][K], W [N][K]: fragments
// are 16 contiguous bytes). Only the ReLU intermediate lives in LDS
// (padded ROW_S layout). 2 barriers total. (Proven in round 1.)
// ---------------------------------------------------------------------------
__launch_bounds__(256, 2)
__global__ void fuse3_k(const u16* __restrict__ Aloc, const u16* __restrict__ Ag,
                        const u16* __restrict__ wtu, const bf16* __restrict__ wtb,
                        const void* __restrict__ cx, void* __restrict__ out,
                        const void* __restrict__ dtp) {
    __shared__ __align__(16) u16 relb[4 * CH_S];
    const int mode = get_mode(dtp);
    const int tid = threadIdx.x;
    const int wave = tid >> 6, lane = tid & 63;
    const int q = lane >> 4, lr = lane & 15;
    const int wm = (wave >> 1) << 5, wn = (wave & 1) << 6;
    const int bm = blockIdx.x << 6;
    const f32x4 zero = {0.f, 0.f, 0.f, 0.f};
    f32x4 acc1[2][4], acc2[2][4];
    #pragma unroll
    for (int i = 0; i < 2; ++i)
        #pragma unroll
        for (int j = 0; j < 4; ++j) { acc1[i][j] = zero; acc2[i][j] = zero; }

    #pragma unroll
    for (int k0 = 0; k0 < 4; ++k0) {
        bf16x8 al[2], ag[2], blf[4], bgf[4];
        #pragma unroll
        for (int t = 0; t < 2; ++t) {
            size_t off = (size_t)(bm + wm + (t << 4) + lr) * 128 + (k0 << 5) + (q << 3);
            al[t] = *(const bf16x8*)(Aloc + off);
            ag[t] = *(const bf16x8*)(Ag + off);
        }
        #pragma unroll
        for (int t = 0; t < 4; ++t) {
            int woff = ((wn + (t << 4) + lr) << 7) + (k0 << 5) + (q << 3);
            blf[t] = *(const bf16x8*)(wtu + O_LFW + woff);
            bgf[t] = *(const bf16x8*)(wtu + O_GFW + woff);
        }
        #pragma unroll
        for (int mt = 0; mt < 2; ++mt)
            #pragma unroll
            for (int nt = 0; nt < 4; ++nt) {
                acc1[mt][nt] = __builtin_amdgcn_mfma_f32_16x16x32_bf16(
                    al[mt], blf[nt], acc1[mt][nt], 0, 0, 0);
                acc2[mt][nt] = __builtin_amdgcn_mfma_f32_16x16x32_bf16(
                    ag[mt], bgf[nt], acc2[mt][nt], 0, 0, 0);
            }
    }
    // relu((local@lf + lfb) * (g@gf + gfb)) -> padded LDS
    #pragma unroll
    for (int nt = 0; nt < 4; ++nt) {
        int c = wn + (nt << 4) + lr;
        float lfb = BF(wtb[O_LFB + c]);
        float gfb = BF(wtb[O_GFB + c]);
        #pragma unroll
        for (int mt = 0; mt < 2; ++mt) {
            #pragma unroll
            for (int i = 0; i < 4; ++i) {
                int r = wm + (mt << 4) + (q << 2) + i;
                float t1 = acc1[mt][nt][i] + lfb;
                float t2 = acc2[mt][nt][i] + gfb;
                float rel = t1 * t2;
                relb[(c >> 5) * CH_S + r * ROW_S + (c & 31)] = FBu(rel > 0.f ? rel : 0.f);
            }
        }
    }
    __syncthreads();
    f32x4 acc3[2][4];
    #pragma unroll
    for (int i = 0; i < 2; ++i)
        #pragma unroll
        for (int j = 0; j < 4; ++j) acc3[i][j] = zero;
    #pragma unroll
    for (int k0 = 0; k0 < 4; ++k0) {
        bf16x8 ar[2], bff[4];
        #pragma unroll
        for (int t = 0; t < 2; ++t)
            ar[t] = *(const bf16x8*)(relb + k0 * CH_S + (wm + (t << 4) + lr) * ROW_S + (q << 3));
        #pragma unroll
        for (int t = 0; t < 4; ++t)
            bff[t] = *(const bf16x8*)(wtu + O_FFW + ((wn + (t << 4) + lr) << 7) + (k0 << 5) + (q << 3));
        #pragma unroll
        for (int mt = 0; mt < 2; ++mt)
            #pragma unroll
            for (int nt = 0; nt < 4; ++nt)
                acc3[mt][nt] = __builtin_amdgcn_mfma_f32_16x16x32_bf16(
                    ar[mt], bff[nt], acc3[mt][nt], 0, 0, 0);
    }
    // LSTM gating epilogue
    #pragma unroll
    for (int nt = 0; nt < 4; ++nt) {
        int col = wn + (nt << 4) + lr;
        float ffb = BF(wtb[O_FFB + col]);
        #pragma unroll
        for (int mt = 0; mt < 2; ++mt) {
            #pragma unroll
            for (int i = 0; i < 4; ++i) {
                int r = bm + wm + (mt << 4) + (q << 2) + i;
                size_t idx = (size_t)r * 128 + col;
                float v = acc3[mt][nt][i] + ffb;
                float gate = 1.f / (1.f + expf(-v));
                float cell = tanhf(v);
                float cy = gate * (LD(cx, idx, mode) + cell);
                float hy = gate * tanhf(cy);
                if (mode) ((float*)out)[idx] = hy;
                else      ((bf16*)out)[idx] = FB(hy);
            }
        }
    }
}

// ---------------------------------------------------------------------------
// Deformable conv1d local branch; bf16 out in (B,C,L) layout.
// ---------------------------------------------------------------------------
__launch_bounds__(256)
__global__ void deform_k(const void* __restrict__ xt, const bf16* __restrict__ wtb,
                         bf16* __restrict__ outL) {
    __shared__ __align__(16) u16 ot[128 * 72];
    __shared__ int s_fp[192], s_cp[192];
    __shared__ float s_al[192], s_mk[192];
    const int mode = get_mode(xt);
    const int tid = threadIdx.x;
    const int wave = tid >> 6, lane = tid & 63;
    const int b = blockIdx.x >> 6;
    const int l0 = (blockIdx.x & 63) << 6;
    float wo[3][3][2], wmk[3][3][2];
    #pragma unroll
    for (int k = 0; k < 3; ++k)
        #pragma unroll
        for (int j = 0; j < 3; ++j) {
            wo[k][j][0]  = BF(wtb[O_OW + (k * 128 + lane) * 3 + j]);
            wo[k][j][1]  = BF(wtb[O_OW + (k * 128 + lane + 64) * 3 + j]);
            wmk[k][j][0] = BF(wtb[O_MW + (k * 128 + lane) * 3 + j]);
            wmk[k][j][1] = BF(wtb[O_MW + (k * 128 + lane + 64) * 3 + j]);
        }
    for (int il = 0; il < 16; ++il) {
        int l_loc = wave * 16 + il;
        int l = l0 + l_loc;
        float a6[6] = {};
        #pragma unroll
        for (int j = 0; j < 3; ++j) {
            int row = l + j - 1;
            if (row >= 0 && row < 4096) {
                size_t base = ((size_t)(b << 12) + row) * 128;
                float x0 = LD(xt, base + lane, mode);
                float x1 = LD(xt, base + lane + 64, mode);
                #pragma unroll
                for (int k = 0; k < 3; ++k) {
                    a6[k]     += x0 * wo[k][j][0]  + x1 * wo[k][j][1];
                    a6[3 + k] += x0 * wmk[k][j][0] + x1 * wmk[k][j][1];
                }
            }
        }
        #pragma unroll
        for (int off = 32; off > 0; off >>= 1)
            #pragma unroll
            for (int k = 0; k < 6; ++k) a6[k] += __shfl_down(a6[k], off);
        if (lane == 0) {
            #pragma unroll
            for (int k = 0; k < 3; ++k) {
                float off = a6[k] + BF(wtb[O_OB + k]);
                float pos = fminf(fmaxf((float)l + off, 0.f), 4095.f);
                float fpf = floorf(pos);
                int fp = (int)fpf;
                int cp = fp + 1 > 4095 ? 4095 : fp + 1;
                s_fp[l_loc * 3 + k] = fp;
                s_cp[l_loc * 3 + k] = cp;
                s_al[l_loc * 3 + k] = pos - fpf;
                float mv = a6[3 + k] + BF(wtb[O_MB + k]);
                s_mk[l_loc * 3 + k] = 1.f / (1.f + expf(-mv));
            }
        }
    }
    __syncthreads();
    {
        int c = tid & 127, lh = tid >> 7;
        for (int it = 0; it < 32; ++it) {
            int l_loc = lh * 32 + it;
            float o = 0.f;
            #pragma unroll
            for (int k = 0; k < 3; ++k) {
                int fp = s_fp[l_loc * 3 + k];
                int cp = s_cp[l_loc * 3 + k];
                float al = s_al[l_loc * 3 + k];
                float mk = s_mk[l_loc * 3 + k];
                float xf = LD(xt, ((size_t)(b << 12) + fp) * 128 + c, mode);
                float xc = LD(xt, ((size_t)(b << 12) + cp) * 128 + c, mode);
                o += (xf * (1.f - al) + xc * al) * mk;
            }
            ot[c * 72 + l_loc] = FBu(o);
        }
    }
    __syncthreads();
    #pragma unroll
    for (int pass = 0; pass < 4; ++pass) {
        int cc = pass * 32 + (tid >> 3);
        int oo = tid & 7;
        const uint4 v = *(const uint4*)(ot + cc * 72 + oo * 8);
        *(uint4*)(outL + (size_t)b * 524288 + (size_t)cc * 4096 + l0 + oo * 8) = v;
    }
}

extern "C" void kernel_launch(void* const* d_in, const int* in_sizes, int n_in,
                              void* d_out, int out_size, void* d_ws, size_t ws_size,
                              hipStream_t stream) {
    (void)out_size; (void)ws_size;
    int I[28] = {0,1,2,3,4,5,6,7,8,9,10,11,12,13,14,15,16,17,18,19,20,21,22,23,24,25,26,27};
    if (n_in >= 28 && in_sizes[7] != 98304 && in_sizes[23] == 98304 && in_sizes[26] == 1800) {
        int alt[28] = {27, 9, 0, 25, 24, 15, 14, 23, 22, 26, 21, 20, 17, 16,
                       2, 1, 4, 3, 19, 18, 13, 12, 11, 10, 8, 7, 6, 5};
        for (int i = 0; i < 28; ++i) I[i] = alt[i];
    }
    const void* xt = d_in[I[0]];
    const void* hx = d_in[I[1]];
    const void* cx = d_in[I[2]];

    char* wsb = (char*)d_ws;
    float* g    = (float*)wsb;                    // fp32 residual [0,16M)
    u16*   Abf  = (u16*)(wsb + 16777216);         // bf16(g)
    u16*   Bbf  = (u16*)(wsb + 25165824);         // Xcat / qkv
    u16*   Cbf  = (u16*)(wsb + 50331648);         // attn-out / local
    bf16*  wtb  = (bf16*)(wsb + 58720256);
    u16*   wtu  = (u16*)wtb;

    Prep p;
    PrepT descs[29] = {
        {d_in[I[3]],  0,     256, 128, O_REDW},
        {d_in[I[7]],  0,     128, 384, O_QKVW},
        {d_in[I[7]],  49152, 128, 384, O_QKVW + 49152},
        {d_in[I[10]], 0,     128, 128, O_PW},
        {d_in[I[10]], 16384, 128, 128, O_PW + 16384},
        {d_in[I[14]], 0,     128, 512, O_F1W},
        {d_in[I[14]], 65536, 128, 512, O_F1W + 65536},
        {d_in[I[16]], 0,     512, 128, O_F2W},
        {d_in[I[16]], 65536, 512, 128, O_F2W + 65536},
        {d_in[I[22]], 0,     128, 128, O_LFW},
        {d_in[I[24]], 0,     128, 128, O_GFW},
        {d_in[I[26]], 0,     128, 128, O_FFW},
        {d_in[I[4]],  0,  128, 0, O_REDB},
        {d_in[I[8]],  0,  768, 0, O_QKVB},
        {d_in[I[11]], 0,  256, 0, O_PB},
        {d_in[I[15]], 0, 1024, 0, O_F1B},
        {d_in[I[17]], 0,  256, 0, O_F2B},
        {d_in[I[23]], 0,  128, 0, O_LFB},
        {d_in[I[25]], 0,  128, 0, O_GFB},
        {d_in[I[27]], 0,  128, 0, O_FFB},
        {d_in[I[9]],  0, 1800, 0, O_RP},
        {d_in[I[5]],  0,  256, 0, O_N1G},
        {d_in[I[6]],  0,  256, 0, O_N1B},
        {d_in[I[12]], 0,  256, 0, O_N2G},
        {d_in[I[13]], 0,  256, 0, O_N2B},
        {d_in[I[18]], 0, 1152, 0, O_OW},
        {d_in[I[19]], 0,    3, 0, O_OB},
        {d_in[I[20]], 0, 1152, 0, O_MW},
        {d_in[I[21]], 0,    3, 0, O_MB},
    };
    int cum = 0;
    for (int i = 0; i < 29; ++i) {
        p.d[i] = descs[i];
        p.start[i] = cum;
        cum += (descs[i].N > 0) ? descs[i].K * descs[i].N : descs[i].K;
    }
    p.start[29] = cum;

    prep_k<<<(cum + 255) / 256, 256, 0, stream>>>(p, wtb, xt);
    xcat_k<<<1024, 256, 0, stream>>>(xt, hx, Bbf);

    // g = Xcat @ red_w + red_b (fp32)
    gemm_mfma<5><<<dim3(1, 512), 256, 0, stream>>>(Bbf, wtu + O_REDW, wtb + O_REDB,
                                                   nullptr, g, 32768, 128, 256, 0);

    for (int d = 0; d < 2; ++d) {
        int shift = d ? 4 : 0;
        qkvln_k<<<512, 256, 0, stream>>>(g, wtu, wtb, Bbf, d, shift);
        attn_k<<<512, 256, 0, stream>>>(Bbf, wtb + O_RP + d * 900, Cbf, shift);
        gemm_mfma<3><<<dim3(1, 512), 256, 0, stream>>>(Cbf, wtu + O_PW + d * 16384,
                                                       wtb + O_PB + d * 128, nullptr, g,
                                                       32768, 128, 128, shift);
        mlp_k<<<512, 256, 0, stream>>>(g, (bf16*)Abf, wtu, wtb, d);
    }

    // local branch -> Cbf (B,C,L)
    deform_k<<<512, 256, 0, stream>>>(xt, wtb, (bf16*)Cbf);
    // fused fusion chain + LSTM -> out
    fuse3_k<<<512, 256, 0, stream>>>(Cbf, Abf, wtu, wtb, cx, d_out, xt);
}